// Round 3
// baseline (749.400 us; speedup 1.0000x reference)
//
#include <hip/hip_runtime.h>
#include <math.h>

// GPT block forward. bf16 MFMA GEMMs (m97 structure) + bf16 MFMA flash attention.
// Shapes: B=4, T=2048, E=1024, H=16, D=64, M=B*T=8192.
//
// Workspace layout (152 MB):
//   [0,  64MB)  region0: qkv bf16 (8192x3072, 48MB) -> later h bf16 (8192x4096, 64MB)
//   [64, 80MB)  xn bf16  (8192x1024)   -- xn1 then xn2
//   [80, 96MB)  attnout bf16 (8192x1024)
//   [96,128MB)  x1 f32   (8192x1024)
//   [128,152MB) weights bf16 transposed [N][K]:
//               w_attnT(6MB) w_attnprojT(2MB) w_fcT(8MB) w_projT(8MB)

constexpr int E_    = 1024;
constexpr int NHEAD = 16;
constexpr int BATCH = 4;
constexpr int TSEQ  = 2048;
constexpr int MROWS = BATCH * TSEQ;   // 8192

typedef unsigned short ushort_t;
typedef short  bf16x8 __attribute__((ext_vector_type(8)));
typedef float  f32x4  __attribute__((ext_vector_type(4)));
typedef unsigned short u16x4 __attribute__((ext_vector_type(4)));
typedef unsigned short u16x8 __attribute__((ext_vector_type(8)));

__device__ __forceinline__ ushort_t f2bf(float f) {
  unsigned u = __float_as_uint(f);
  unsigned r = (u + 0x7fffu + ((u >> 16) & 1u)) >> 16;
  return (ushort_t)r;
}

__device__ __forceinline__ void gload_lds16(const void* g, void* l) {
  __builtin_amdgcn_global_load_lds(
      (const __attribute__((address_space(1))) void*)g,
      (__attribute__((address_space(3))) void*)l, 16, 0, 0);
}

// XOR-swizzle for [rows][64] bf16 LDS tiles (128B rows): byte ^= ((row&7)<<4)
// == u16 index: row*64 + (col ^ ((row&7)<<3)). Keeps 8-u16 alignment.
__device__ __forceinline__ int swz64(int row, int col) {
  return row * 64 + (col ^ ((row & 7) << 3));
}

// ------------------------------------------------- weight cast + transpose
__global__ __launch_bounds__(256) void castT_kernel(const float* __restrict__ W,
                                                    ushort_t* __restrict__ Wt,
                                                    int K, int N) {
  const int n = blockIdx.x * 64 + (threadIdx.x & 63);
  const int k = blockIdx.y * 32 + (threadIdx.x >> 6) * 8;
  ushort_t v[8];
  #pragma unroll
  for (int u = 0; u < 8; ++u) v[u] = f2bf(W[(size_t)(k + u) * N + n]);
  *(u16x8*)&Wt[(size_t)n * K + k] = *(const u16x8*)v;
}

// ---------------------------------------------------------------- LayerNorm
__global__ __launch_bounds__(256) void ln_kernel(const float* __restrict__ x,
                                                 const float* __restrict__ g,
                                                 const float* __restrict__ b,
                                                 ushort_t* __restrict__ y) {
  const int row = blockIdx.x;
  const float4* xr = reinterpret_cast<const float4*>(x + (size_t)row * E_);
  float4 v = xr[threadIdx.x];
  float s  = v.x + v.y + v.z + v.w;
  float ss = v.x * v.x + v.y * v.y + v.z * v.z + v.w * v.w;
  #pragma unroll
  for (int off = 32; off > 0; off >>= 1) {
    s  += __shfl_down(s, off);
    ss += __shfl_down(ss, off);
  }
  __shared__ float red[8];
  __shared__ float stats[2];
  const int wid = threadIdx.x >> 6;
  if ((threadIdx.x & 63) == 0) { red[wid] = s; red[4 + wid] = ss; }
  __syncthreads();
  if (threadIdx.x == 0) {
    float S  = red[0] + red[1] + red[2] + red[3];
    float SS = red[4] + red[5] + red[6] + red[7];
    float mu  = S * (1.0f / E_);
    float var = SS * (1.0f / E_) - mu * mu;
    stats[0] = mu;
    stats[1] = rsqrtf(var + 1e-5f);
  }
  __syncthreads();
  const float mu = stats[0], rstd = stats[1];
  float4 gv = reinterpret_cast<const float4*>(g)[threadIdx.x];
  float4 bv = reinterpret_cast<const float4*>(b)[threadIdx.x];
  u16x4 o;
  o[0] = f2bf((v.x - mu) * rstd * gv.x + bv.x);
  o[1] = f2bf((v.y - mu) * rstd * gv.y + bv.y);
  o[2] = f2bf((v.z - mu) * rstd * gv.z + bv.z);
  o[3] = f2bf((v.w - mu) * rstd * gv.w + bv.w);
  *(u16x4*)(y + (size_t)row * E_ + threadIdx.x * 4) = o;
}

// ------------------------------------------------------------ bf16 MFMA GEMM
// C[M,N] = A[M,K](bf16) @ Wt[N,K](bf16)^T + bias (+GELU) (+res f32).
template <int GELU, int RES, int OBF>
__global__ __launch_bounds__(256) void gemm_kernel(
    const ushort_t* __restrict__ A, const ushort_t* __restrict__ Wt,
    const float* __restrict__ bias, const float* __restrict__ res,
    void* __restrict__ Cout, int M, int N, int K) {
  constexpr int BK = 64;
  __shared__ ushort_t As[128][BK];
  __shared__ ushort_t Bs[128][BK];

  const int t    = threadIdx.x;
  const int lane = t & 63;
  const int wave = t >> 6;
  const int wr   = wave >> 1, wc = wave & 1;
  const int bm   = blockIdx.y * 128, bn = blockIdx.x * 128;

  const f32x4 zero = {0.f, 0.f, 0.f, 0.f};
  f32x4 acc[4][4];
  #pragma unroll
  for (int mi = 0; mi < 4; ++mi)
    #pragma unroll
    for (int ni = 0; ni < 4; ++ni) acc[mi][ni] = zero;

  const int srow  = 32 * wave + (lane >> 3);
  const int skoff = (lane & 7) * 8;
  const ushort_t* gA = A  + (size_t)(bm + srow) * K + skoff;
  const ushort_t* gB = Wt + (size_t)(bn + srow) * K + skoff;

  for (int k0 = 0; k0 < K; k0 += BK) {
    #pragma unroll
    for (int i = 0; i < 4; ++i) {
      gload_lds16(gA + (size_t)(i * 8) * K + k0, &As[32 * wave + i * 8][0]);
      gload_lds16(gB + (size_t)(i * 8) * K + k0, &Bs[32 * wave + i * 8][0]);
    }
    __syncthreads();

    #pragma unroll
    for (int kk = 0; kk < 2; ++kk) {
      bf16x8 af[4], bfr[4];
      #pragma unroll
      for (int mi = 0; mi < 4; ++mi)
        af[mi] = *(const bf16x8*)&As[wr * 64 + mi * 16 + (lane & 15)]
                                    [kk * 32 + (lane >> 4) * 8];
      #pragma unroll
      for (int ni = 0; ni < 4; ++ni)
        bfr[ni] = *(const bf16x8*)&Bs[wc * 64 + ni * 16 + (lane & 15)]
                                     [kk * 32 + (lane >> 4) * 8];
      #pragma unroll
      for (int mi = 0; mi < 4; ++mi)
        #pragma unroll
        for (int ni = 0; ni < 4; ++ni)
          acc[mi][ni] = __builtin_amdgcn_mfma_f32_16x16x32_bf16(
              af[mi], bfr[ni], acc[mi][ni], 0, 0, 0);
    }
    __syncthreads();
  }

  float biasv[4];
  #pragma unroll
  for (int ni = 0; ni < 4; ++ni)
    biasv[ni] = bias[bn + wc * 64 + ni * 16 + (lane & 15)];
  const int ccol = bn + wc * 64 + (lane & 15);

  #pragma unroll
  for (int mi = 0; mi < 4; ++mi) {
    #pragma unroll
    for (int j = 0; j < 4; ++j) {
      const int row = bm + wr * 64 + mi * 16 + (lane >> 4) * 4 + j;
      const size_t rbase = (size_t)row * N;
      #pragma unroll
      for (int ni = 0; ni < 4; ++ni) {
        float v = acc[mi][ni][j] + biasv[ni];
        if (GELU) v = 0.5f * v * (1.0f + erff(v * 0.70710678118654752f));
        if (RES)  v += res[rbase + ccol + ni * 16];
        if (OBF)  ((ushort_t*)Cout)[rbase + ccol + ni * 16] = f2bf(v);
        else      ((float*)Cout)[rbase + ccol + ni * 16] = v;
      }
    }
  }
}

// ---------------------------------------------------------- MFMA attention
// Causal flash attention, bf16 MFMA, fp32 online softmax.
// Block = 256 thr (4 waves) x one (b,h) x 128 q-rows. Wave owns 32 q-rows.
// KV tiles of 64. K/Vt staged in XOR-swizzled LDS; P transposed via per-wave
// LDS round-trip. Q kept in registers.
__global__ __launch_bounds__(256) void attn_kernel(const ushort_t* __restrict__ qkv,
                                                   ushort_t* __restrict__ out) {
  __shared__ ushort_t Ks[64 * 64];      // swizzled [k][d]
  __shared__ ushort_t Vt[64 * 64];      // swizzled [d][k]
  __shared__ ushort_t Ps[4][32 * 64];   // per-wave swizzled [q][k]

  const int qb  = gridDim.x - 1 - blockIdx.x;   // heavy blocks first
  const int b   = blockIdx.y >> 4;
  const int hd  = blockIdx.y & 15;
  const int t   = threadIdx.x;
  const int lane = t & 63, w = t >> 6;
  const int l15 = lane & 15, l4 = lane >> 4;

  const size_t rs3 = 3 * E_;
  const ushort_t* base = qkv + (size_t)b * TSEQ * rs3 + hd * 64;

  // staging coords: thread covers row (t>>2), 16 cols at (t&3)*16
  const int srow = t >> 2;
  const int sc0  = (t & 3) * 16;

  // Q fragments (raw, scale folded into S later)
  bf16x8 qfrag[2][2];
  #pragma unroll
  for (int qs = 0; qs < 2; ++qs)
    #pragma unroll
    for (int h = 0; h < 2; ++h)
      qfrag[qs][h] = *(const bf16x8*)(base +
          (size_t)(qb * 128 + w * 32 + qs * 16 + l15) * rs3 + h * 32 + l4 * 8);

  float mrun[2][4], lrun[2][4];
  f32x4 oacc[2][4];
  #pragma unroll
  for (int qs = 0; qs < 2; ++qs) {
    #pragma unroll
    for (int r = 0; r < 4; ++r) { mrun[qs][r] = -INFINITY; lrun[qs][r] = 0.f; }
    #pragma unroll
    for (int c = 0; c < 4; ++c) oacc[qs][c] = f32x4{0.f, 0.f, 0.f, 0.f};
  }

  const int qrow0 = qb * 128 + w * 32;   // wave's min q row
  const int nt = 2 * qb + 2;

  for (int kt = 0; kt < nt; ++kt) {
    __syncthreads();   // prev tile's K/Vt reads complete
    {
      const ushort_t* ksrc = base + E_ + (size_t)(kt * 64 + srow) * rs3 + sc0;
      u16x8 k0 = *(const u16x8*)ksrc;
      u16x8 k1 = *(const u16x8*)(ksrc + 8);
      u16x8 v0 = *(const u16x8*)(ksrc + E_);
      u16x8 v1 = *(const u16x8*)(ksrc + E_ + 8);
      *(u16x8*)&Ks[swz64(srow, sc0)]     = k0;
      *(u16x8*)&Ks[swz64(srow, sc0 + 8)] = k1;
      #pragma unroll
      for (int j = 0; j < 8; ++j) {
        Vt[swz64(sc0 + j, srow)]     = v0[j];
        Vt[swz64(sc0 + 8 + j, srow)] = v1[j];
      }
    }
    __syncthreads();

    // ---- S = Q K^T  (S[q][k], col=k=l15, row=q=l4*4+r)
    f32x4 s[2][4];
    #pragma unroll
    for (int ct = 0; ct < 4; ++ct) {
      bf16x8 kf0 = *(const bf16x8*)&Ks[swz64(ct * 16 + l15, l4 * 8)];
      bf16x8 kf1 = *(const bf16x8*)&Ks[swz64(ct * 16 + l15, 32 + l4 * 8)];
      #pragma unroll
      for (int qs = 0; qs < 2; ++qs) {
        f32x4 acc = __builtin_amdgcn_mfma_f32_16x16x32_bf16(
            qfrag[qs][0], kf0, f32x4{0.f, 0.f, 0.f, 0.f}, 0, 0, 0);
        s[qs][ct] = __builtin_amdgcn_mfma_f32_16x16x32_bf16(
            qfrag[qs][1], kf1, acc, 0, 0, 0);
      }
    }

    // ---- scale + causal mask
    const int kcol0 = kt * 64;
    const bool domask = (kcol0 + 63) > qrow0;
    #pragma unroll
    for (int qs = 0; qs < 2; ++qs)
      #pragma unroll
      for (int ct = 0; ct < 4; ++ct) {
        s[qs][ct] *= 0.125f;
        if (domask) {
          const int kc = kcol0 + ct * 16 + l15;
          #pragma unroll
          for (int r = 0; r < 4; ++r)
            if (kc > qrow0 + qs * 16 + l4 * 4 + r) s[qs][ct][r] = -INFINITY;
        }
      }

    // ---- online softmax (row spread: 4 regs x 4 ct x 16 lanes of l15)
    #pragma unroll
    for (int qs = 0; qs < 2; ++qs)
      #pragma unroll
      for (int r = 0; r < 4; ++r) {
        float mt = fmaxf(fmaxf(s[qs][0][r], s[qs][1][r]),
                         fmaxf(s[qs][2][r], s[qs][3][r]));
        mt = fmaxf(mt, __shfl_xor(mt, 1));
        mt = fmaxf(mt, __shfl_xor(mt, 2));
        mt = fmaxf(mt, __shfl_xor(mt, 4));
        mt = fmaxf(mt, __shfl_xor(mt, 8));
        const float mnew = fmaxf(mrun[qs][r], mt);
        const float esc  = __expf(mrun[qs][r] - mnew);
        float rsum = 0.f;
        #pragma unroll
        for (int ct = 0; ct < 4; ++ct) {
          const float pv = __expf(s[qs][ct][r] - mnew);
          s[qs][ct][r] = pv;
          rsum += pv;
        }
        rsum += __shfl_xor(rsum, 1);
        rsum += __shfl_xor(rsum, 2);
        rsum += __shfl_xor(rsum, 4);
        rsum += __shfl_xor(rsum, 8);
        lrun[qs][r] = lrun[qs][r] * esc + rsum;
        mrun[qs][r] = mnew;
        #pragma unroll
        for (int c = 0; c < 4; ++c) oacc[qs][c][r] *= esc;
      }

    // ---- P -> per-wave LDS (transpose D-layout -> A-frag layout)
    #pragma unroll
    for (int qs = 0; qs < 2; ++qs)
      #pragma unroll
      for (int ct = 0; ct < 4; ++ct)
        #pragma unroll
        for (int r = 0; r < 4; ++r)
          Ps[w][swz64(qs * 16 + l4 * 4 + r, ct * 16 + l15)] = f2bf(s[qs][ct][r]);

    // ---- O += P V   (A=P rows=q, B=Vt rows=d)
    bf16x8 pa[2][2];
    #pragma unroll
    for (int qs = 0; qs < 2; ++qs)
      #pragma unroll
      for (int kk = 0; kk < 2; ++kk)
        pa[qs][kk] = *(const bf16x8*)&Ps[w][swz64(qs * 16 + l15, kk * 32 + l4 * 8)];
    #pragma unroll
    for (int ct2 = 0; ct2 < 4; ++ct2) {
      bf16x8 vb0 = *(const bf16x8*)&Vt[swz64(ct2 * 16 + l15, l4 * 8)];
      bf16x8 vb1 = *(const bf16x8*)&Vt[swz64(ct2 * 16 + l15, 32 + l4 * 8)];
      #pragma unroll
      for (int qs = 0; qs < 2; ++qs) {
        oacc[qs][ct2] = __builtin_amdgcn_mfma_f32_16x16x32_bf16(
            pa[qs][0], vb0, oacc[qs][ct2], 0, 0, 0);
        oacc[qs][ct2] = __builtin_amdgcn_mfma_f32_16x16x32_bf16(
            pa[qs][1], vb1, oacc[qs][ct2], 0, 0, 0);
      }
    }
  }

  // ---- epilogue: O/l -> bf16
  #pragma unroll
  for (int qs = 0; qs < 2; ++qs)
    #pragma unroll
    for (int r = 0; r < 4; ++r) {
      const float inv = 1.0f / lrun[qs][r];
      const int qg = qb * 128 + w * 32 + qs * 16 + l4 * 4 + r;
      ushort_t* dst = out + (size_t)(b * TSEQ + qg) * E_ + hd * 64 + l15;
      #pragma unroll
      for (int ct2 = 0; ct2 < 4; ++ct2)
        dst[ct2 * 16] = f2bf(oacc[qs][ct2][r] * inv);
    }
}

// ---------------------------------------------------------------- launcher
extern "C" void kernel_launch(void* const* d_in, const int* in_sizes, int n_in,
                              void* d_out, int out_size, void* d_ws, size_t ws_size,
                              hipStream_t stream) {
  const float* x          = (const float*)d_in[0];
  const float* ln1_g      = (const float*)d_in[1];
  const float* ln1_b      = (const float*)d_in[2];
  const float* w_attn     = (const float*)d_in[3];
  const float* b_attn     = (const float*)d_in[4];
  const float* w_attnproj = (const float*)d_in[5];
  const float* b_attnproj = (const float*)d_in[6];
  const float* ln2_g      = (const float*)d_in[7];
  const float* ln2_b      = (const float*)d_in[8];
  const float* w_fc       = (const float*)d_in[9];
  const float* b_fc       = (const float*)d_in[10];
  const float* w_proj     = (const float*)d_in[11];
  const float* b_proj     = (const float*)d_in[12];
  float* out = (float*)d_out;

  char* ws = (char*)d_ws;
  const size_t MB = 1024 * 1024;
  ushort_t* qkv      = (ushort_t*)ws;                    // 48 MB bf16
  ushort_t* h_bf     = (ushort_t*)ws;                    // 64 MB bf16 (alias)
  ushort_t* xn       = (ushort_t*)(ws + 64 * MB);        // 16 MB
  ushort_t* attnout  = (ushort_t*)(ws + 80 * MB);        // 16 MB
  float*    x1       = (float*)(ws + 96 * MB);           // 32 MB
  ushort_t* w_attnT  = (ushort_t*)(ws + 128 * MB);       // 6 MB  [3072][1024]
  ushort_t* w_aprojT = w_attnT  + (size_t)3 * E_ * E_;   // 2 MB  [1024][1024]
  ushort_t* w_fcT    = w_aprojT + (size_t)E_ * E_;       // 8 MB  [4096][1024]
  ushort_t* w_projT  = w_fcT    + (size_t)4 * E_ * E_;   // 8 MB  [1024][4096]

  castT_kernel<<<dim3(3 * E_ / 64, E_ / 32), 256, 0, stream>>>(w_attn, w_attnT, E_, 3 * E_);
  castT_kernel<<<dim3(E_ / 64, E_ / 32), 256, 0, stream>>>(w_attnproj, w_aprojT, E_, E_);
  castT_kernel<<<dim3(4 * E_ / 64, E_ / 32), 256, 0, stream>>>(w_fc, w_fcT, E_, 4 * E_);
  castT_kernel<<<dim3(E_ / 64, 4 * E_ / 32), 256, 0, stream>>>(w_proj, w_projT, 4 * E_, E_);

  // 1) xn1 = LN(x) -> bf16
  ln_kernel<<<MROWS, 256, 0, stream>>>(x, ln1_g, ln1_b, xn);
  // 2) qkv = xn1 @ w_attn + b_attn -> bf16
  gemm_kernel<0, 0, 1><<<dim3(3 * E_ / 128, MROWS / 128), 256, 0, stream>>>(
      xn, w_attnT, b_attn, nullptr, qkv, MROWS, 3 * E_, E_);
  // 3) attnout = causal_attention(qkv) -> bf16
  attn_kernel<<<dim3(TSEQ / 128, BATCH * NHEAD), 256, 0, stream>>>(qkv, attnout);
  // 4) x1 = x + attnout @ w_attnproj + b_attnproj -> f32
  gemm_kernel<0, 1, 0><<<dim3(E_ / 128, MROWS / 128), 256, 0, stream>>>(
      attnout, w_aprojT, b_attnproj, x, x1, MROWS, E_, E_);
  // 5) xn2 = LN(x1) -> bf16
  ln_kernel<<<MROWS, 256, 0, stream>>>(x1, ln2_g, ln2_b, xn);
  // 6) h = gelu(xn2 @ w_fc + b_fc) -> bf16 (region0, qkv dead)
  gemm_kernel<1, 0, 1><<<dim3(4 * E_ / 128, MROWS / 128), 256, 0, stream>>>(
      xn, w_fcT, b_fc, nullptr, h_bf, MROWS, 4 * E_, E_);
  // 7) out = x1 + h @ w_proj + b_proj -> f32
  gemm_kernel<0, 1, 0><<<dim3(E_ / 128, MROWS / 128), 256, 0, stream>>>(
      h_bf, w_projT, b_proj, x1, out, MROWS, E_, 4 * E_);
}

// Round 5
// 659.161 us; speedup vs baseline: 1.1369x; 1.1369x over previous
//
#include <hip/hip_runtime.h>
#include <math.h>

// GPT block forward. bf16 MFMA GEMMs (m97 structure) + bf16 MFMA flash attention
// (swapped-QK^T layout, async K/V staging, double-buffered K).
// Shapes: B=4, T=2048, E=1024, H=16, D=64, M=B*T=8192.
//
// Workspace layout (152 MB):
//   [0,  64MB)  region0: qkv bf16 (8192x3072, 48MB) -> later h bf16 (8192x4096, 64MB)
//   [64, 80MB)  xn bf16  (8192x1024)   -- xn1 then xn2
//   [80, 96MB)  attnout bf16 (8192x1024)
//   [96,128MB)  x1 f32   (8192x1024)
//   [128,152MB) weights bf16 transposed [N][K]:
//               w_attnT(6MB) w_attnprojT(2MB) w_fcT(8MB) w_projT(8MB)

constexpr int E_    = 1024;
constexpr int NHEAD = 16;
constexpr int BATCH = 4;
constexpr int TSEQ  = 2048;
constexpr int MROWS = BATCH * TSEQ;   // 8192

typedef unsigned short ushort_t;
typedef short  bf16x8 __attribute__((ext_vector_type(8)));
typedef float  f32x4  __attribute__((ext_vector_type(4)));
typedef unsigned short u16x4 __attribute__((ext_vector_type(4)));
typedef unsigned short u16x8 __attribute__((ext_vector_type(8)));

__device__ __forceinline__ ushort_t f2bf(float f) {
  unsigned u = __float_as_uint(f);
  unsigned r = (u + 0x7fffu + ((u >> 16) & 1u)) >> 16;
  return (ushort_t)r;
}

__device__ __forceinline__ void gload_lds16(const void* g, void* l) {
  __builtin_amdgcn_global_load_lds(
      (const __attribute__((address_space(1))) void*)g,
      (__attribute__((address_space(3))) void*)l, 16, 0, 0);
}

// ------------------------------------------------- weight cast + transpose
__global__ __launch_bounds__(256) void castT_kernel(const float* __restrict__ W,
                                                    ushort_t* __restrict__ Wt,
                                                    int K, int N) {
  const int n = blockIdx.x * 64 + (threadIdx.x & 63);
  const int k = blockIdx.y * 32 + (threadIdx.x >> 6) * 8;
  ushort_t v[8];
  #pragma unroll
  for (int u = 0; u < 8; ++u) v[u] = f2bf(W[(size_t)(k + u) * N + n]);
  *(u16x8*)&Wt[(size_t)n * K + k] = *(const u16x8*)v;
}

// ---------------------------------------------------------------- LayerNorm
__global__ __launch_bounds__(256) void ln_kernel(const float* __restrict__ x,
                                                 const float* __restrict__ g,
                                                 const float* __restrict__ b,
                                                 ushort_t* __restrict__ y) {
  const int row = blockIdx.x;
  const float4* xr = reinterpret_cast<const float4*>(x + (size_t)row * E_);
  float4 v = xr[threadIdx.x];
  float s  = v.x + v.y + v.z + v.w;
  float ss = v.x * v.x + v.y * v.y + v.z * v.z + v.w * v.w;
  #pragma unroll
  for (int off = 32; off > 0; off >>= 1) {
    s  += __shfl_down(s, off);
    ss += __shfl_down(ss, off);
  }
  __shared__ float red[8];
  __shared__ float stats[2];
  const int wid = threadIdx.x >> 6;
  if ((threadIdx.x & 63) == 0) { red[wid] = s; red[4 + wid] = ss; }
  __syncthreads();
  if (threadIdx.x == 0) {
    float S  = red[0] + red[1] + red[2] + red[3];
    float SS = red[4] + red[5] + red[6] + red[7];
    float mu  = S * (1.0f / E_);
    float var = SS * (1.0f / E_) - mu * mu;
    stats[0] = mu;
    stats[1] = rsqrtf(var + 1e-5f);
  }
  __syncthreads();
  const float mu = stats[0], rstd = stats[1];
  float4 gv = reinterpret_cast<const float4*>(g)[threadIdx.x];
  float4 bv = reinterpret_cast<const float4*>(b)[threadIdx.x];
  u16x4 o;
  o[0] = f2bf((v.x - mu) * rstd * gv.x + bv.x);
  o[1] = f2bf((v.y - mu) * rstd * gv.y + bv.y);
  o[2] = f2bf((v.z - mu) * rstd * gv.z + bv.z);
  o[3] = f2bf((v.w - mu) * rstd * gv.w + bv.w);
  *(u16x4*)(y + (size_t)row * E_ + threadIdx.x * 4) = o;
}

// ------------------------------------------------------------ bf16 MFMA GEMM
// C[M,N] = A[M,K](bf16) @ Wt[N,K](bf16)^T + bias (+GELU) (+res f32).
template <int GELU, int RES, int OBF>
__global__ __launch_bounds__(256) void gemm_kernel(
    const ushort_t* __restrict__ A, const ushort_t* __restrict__ Wt,
    const float* __restrict__ bias, const float* __restrict__ res,
    void* __restrict__ Cout, int M, int N, int K) {
  constexpr int BK = 64;
  __shared__ ushort_t As[128][BK];
  __shared__ ushort_t Bs[128][BK];

  const int t    = threadIdx.x;
  const int lane = t & 63;
  const int wave = t >> 6;
  const int wr   = wave >> 1, wc = wave & 1;
  const int bm   = blockIdx.y * 128, bn = blockIdx.x * 128;

  const f32x4 zero = {0.f, 0.f, 0.f, 0.f};
  f32x4 acc[4][4];
  #pragma unroll
  for (int mi = 0; mi < 4; ++mi)
    #pragma unroll
    for (int ni = 0; ni < 4; ++ni) acc[mi][ni] = zero;

  const int srow  = 32 * wave + (lane >> 3);
  const int skoff = (lane & 7) * 8;
  const ushort_t* gA = A  + (size_t)(bm + srow) * K + skoff;
  const ushort_t* gB = Wt + (size_t)(bn + srow) * K + skoff;

  for (int k0 = 0; k0 < K; k0 += BK) {
    #pragma unroll
    for (int i = 0; i < 4; ++i) {
      gload_lds16(gA + (size_t)(i * 8) * K + k0, &As[32 * wave + i * 8][0]);
      gload_lds16(gB + (size_t)(i * 8) * K + k0, &Bs[32 * wave + i * 8][0]);
    }
    __syncthreads();

    #pragma unroll
    for (int kk = 0; kk < 2; ++kk) {
      bf16x8 af[4], bfr[4];
      #pragma unroll
      for (int mi = 0; mi < 4; ++mi)
        af[mi] = *(const bf16x8*)&As[wr * 64 + mi * 16 + (lane & 15)]
                                    [kk * 32 + (lane >> 4) * 8];
      #pragma unroll
      for (int ni = 0; ni < 4; ++ni)
        bfr[ni] = *(const bf16x8*)&Bs[wc * 64 + ni * 16 + (lane & 15)]
                                     [kk * 32 + (lane >> 4) * 8];
      #pragma unroll
      for (int mi = 0; mi < 4; ++mi)
        #pragma unroll
        for (int ni = 0; ni < 4; ++ni)
          acc[mi][ni] = __builtin_amdgcn_mfma_f32_16x16x32_bf16(
              af[mi], bfr[ni], acc[mi][ni], 0, 0, 0);
    }
    __syncthreads();
  }

  float biasv[4];
  #pragma unroll
  for (int ni = 0; ni < 4; ++ni)
    biasv[ni] = bias[bn + wc * 64 + ni * 16 + (lane & 15)];
  const int ccol = bn + wc * 64 + (lane & 15);

  #pragma unroll
  for (int mi = 0; mi < 4; ++mi) {
    #pragma unroll
    for (int j = 0; j < 4; ++j) {
      const int row = bm + wr * 64 + mi * 16 + (lane >> 4) * 4 + j;
      const size_t rbase = (size_t)row * N;
      #pragma unroll
      for (int ni = 0; ni < 4; ++ni) {
        float v = acc[mi][ni][j] + biasv[ni];
        if (GELU) v = 0.5f * v * (1.0f + erff(v * 0.70710678118654752f));
        if (RES)  v += res[rbase + ccol + ni * 16];
        if (OBF)  ((ushort_t*)Cout)[rbase + ccol + ni * 16] = f2bf(v);
        else      ((float*)Cout)[rbase + ccol + ni * 16] = v;
      }
    }
  }
}

// ---------------------------------------------------------- MFMA attention
// Causal flash attention, bf16 MFMA, fp32 online softmax, swapped QK^T.
// Block = 256 thr (4 waves) x one (b,h) x 128 q-rows; wave owns 32 q-rows.
// KV tiles of 64. S^T = mfma(K, Q): col=q=l15, row=k -> softmax k-reduction is
// 15 in-lane fmax + 2 shfl_xor; P lands 4-consecutive-in-k -> ds_write_b64.
// K double-buffered via global_load_lds w/ pre-swizzled source; V reg-staged
// async (T14) then transposed into swizzled Vt.
__global__ __launch_bounds__(256) void attn_kernel(const ushort_t* __restrict__ qkv,
                                                   ushort_t* __restrict__ out) {
  __shared__ ushort_t Ks[2][64 * 64];   // [k][d], chunk-swizzled (row&7)
  __shared__ ushort_t Vt[64 * 64];      // [d][k], swizzled key=(d+(d>>4))&7
  __shared__ ushort_t Ps[4][32 * 64];   // per-wave [q][k], swizzled (q&7)

  const int qb  = (int)gridDim.x - 1 - (int)blockIdx.x;   // heavy blocks first
  const int b   = blockIdx.y >> 4;
  const int hd  = blockIdx.y & 15;
  const int t   = threadIdx.x;
  const int lane = t & 63, w = t >> 6;
  const int l15 = lane & 15, l4 = lane >> 4;

  const size_t rs3 = 3 * E_;
  const ushort_t* base = qkv + (size_t)b * TSEQ * rs3 + hd * 64;
  const int q0w = qb * 128 + w * 32;    // wave's min q row

  // staging coords: thread covers V row (t>>2), 16 cols at (t&3)*16
  const int srow = t >> 2;
  const int sc0  = (t & 3) * 16;

  // Q fragments: qf[qs][kk] = Q[q0w+qs*16+l15][kk*32 + l4*8 ..+8]
  bf16x8 qf[2][2];
  #pragma unroll
  for (int qs = 0; qs < 2; ++qs)
    #pragma unroll
    for (int kk = 0; kk < 2; ++kk)
      qf[qs][kk] = *(const bf16x8*)(base +
          (size_t)(q0w + qs * 16 + l15) * rs3 + kk * 32 + l4 * 8);

  float mrun[2], lrun[2];
  f32x4 oacc[2][4];
  #pragma unroll
  for (int qs = 0; qs < 2; ++qs) {
    mrun[qs] = -INFINITY; lrun[qs] = 0.f;
    #pragma unroll
    for (int c = 0; c < 4; ++c) oacc[qs][c] = f32x4{0.f, 0.f, 0.f, 0.f};
  }

  // V prefetch registers
  u16x8 v0, v1;

  // ---- staging helpers (inlined via lambdas)
  auto stageK = [&](int kt, int buf) {
    #pragma unroll
    for (int c = 0; c < 2; ++c) {
      const int lrow  = w * 16 + c * 8 + (lane >> 3);
      const int chunk = (lane & 7) ^ (lane >> 3);   // inverse swizzle on source
      gload_lds16(base + E_ + (size_t)(kt * 64 + lrow) * rs3 + chunk * 8,
                  &Ks[buf][(w * 16 + c * 8) * 64]);
    }
  };
  auto loadV = [&](int kt) {
    const ushort_t* vsrc = base + 2 * E_ + (size_t)(kt * 64 + srow) * rs3 + sc0;
    v0 = *(const u16x8*)vsrc;
    v1 = *(const u16x8*)(vsrc + 8);
  };
  auto writeVt = [&]() {
    #pragma unroll
    for (int j = 0; j < 8; ++j) {
      const int d0 = sc0 + j;
      const int d1 = sc0 + 8 + j;
      Vt[d0 * 64 + (srow ^ (((d0 + (d0 >> 4)) & 7) << 3))] = v0[j];
      Vt[d1 * 64 + (srow ^ (((d1 + (d1 >> 4)) & 7) << 3))] = v1[j];
    }
  };

  // prologue: tile 0
  stageK(0, 0);
  loadV(0);
  writeVt();          // compiler waits vmcnt for v0/v1
  __syncthreads();    // drains gload vmcnt; Ks[0]+Vt ready

  const int nt = 2 * qb + 2;
  int cur = 0;
  const f32x4 zero = {0.f, 0.f, 0.f, 0.f};

  for (int kt = 0; kt < nt; ++kt) {
    // async prefetch of next tile (hidden under this tile's compute)
    if (kt + 1 < nt) { stageK(kt + 1, cur ^ 1); loadV(kt + 1); }

    // ---- S^T = K Q^T : col=q=l15(+16qs), row=k=ct*16+l4*4+r
    f32x4 s[2][4];
    #pragma unroll
    for (int ct = 0; ct < 4; ++ct) {
      const int krow = ct * 16 + l15;
      const int ksw  = (krow & 7) << 3;
      bf16x8 kf0 = *(const bf16x8*)&Ks[cur][krow * 64 + ((l4 * 8) ^ ksw)];
      bf16x8 kf1 = *(const bf16x8*)&Ks[cur][krow * 64 + ((32 + l4 * 8) ^ ksw)];
      #pragma unroll
      for (int qs = 0; qs < 2; ++qs) {
        f32x4 acc = __builtin_amdgcn_mfma_f32_16x16x32_bf16(kf0, qf[qs][0], zero, 0, 0, 0);
        s[qs][ct] = __builtin_amdgcn_mfma_f32_16x16x32_bf16(kf1, qf[qs][1], acc, 0, 0, 0);
      }
    }

    // ---- scale + causal mask (only tiles overlapping the diagonal)
    const int ktb = kt * 64;
    const bool domask = (ktb + 63 > q0w);
    #pragma unroll
    for (int qs = 0; qs < 2; ++qs)
      #pragma unroll
      for (int ct = 0; ct < 4; ++ct) {
        s[qs][ct] *= 0.125f;
        if (domask) {
          const int q = q0w + qs * 16 + l15;
          #pragma unroll
          for (int r = 0; r < 4; ++r)
            if (ktb + ct * 16 + l4 * 4 + r > q) s[qs][ct][r] = -INFINITY;
        }
      }

    // ---- online softmax per q-column (k spread: 16 in-lane + l4 groups)
    float escq[2];
    #pragma unroll
    for (int qs = 0; qs < 2; ++qs) {
      float mt = s[qs][0][0];
      #pragma unroll
      for (int ct = 0; ct < 4; ++ct)
        #pragma unroll
        for (int r = 0; r < 4; ++r) mt = fmaxf(mt, s[qs][ct][r]);
      mt = fmaxf(mt, __shfl_xor(mt, 16));
      mt = fmaxf(mt, __shfl_xor(mt, 32));
      const float mnew = fmaxf(mrun[qs], mt);
      escq[qs] = __expf(mrun[qs] - mnew);   // 0 when mrun=-inf
      float rs = 0.f;
      #pragma unroll
      for (int ct = 0; ct < 4; ++ct)
        #pragma unroll
        for (int r = 0; r < 4; ++r) {
          const float pv = __expf(s[qs][ct][r] - mnew);
          s[qs][ct][r] = pv;
          rs += pv;
        }
      rs += __shfl_xor(rs, 16);
      rs += __shfl_xor(rs, 32);
      lrun[qs] = lrun[qs] * escq[qs] + rs;
      mrun[qs] = mnew;
    }

    // ---- O rescale (O rows q=l4*4+r need esc from lane l4*4+r)
    #pragma unroll
    for (int qs = 0; qs < 2; ++qs)
      #pragma unroll
      for (int r = 0; r < 4; ++r) {
        const float eo = __shfl(escq[qs], l4 * 4 + r);
        #pragma unroll
        for (int ct2 = 0; ct2 < 4; ++ct2) oacc[qs][ct2][r] *= eo;
      }

    // ---- P -> per-wave LDS (4 consecutive k per lane: ds_write_b64)
    const int psw = (l15 & 7) << 3;
    #pragma unroll
    for (int qs = 0; qs < 2; ++qs)
      #pragma unroll
      for (int ct = 0; ct < 4; ++ct) {
        u16x4 pk;
        #pragma unroll
        for (int r = 0; r < 4; ++r) pk[r] = f2bf(s[qs][ct][r]);
        *(u16x4*)&Ps[w][(qs * 16 + l15) * 64 + ((ct * 16 + l4 * 4) ^ psw)] = pk;
      }

    // ---- O += P V  (A=P rows=q, B=Vt rows=d)
    bf16x8 pa[2][2];
    #pragma unroll
    for (int qs = 0; qs < 2; ++qs)
      #pragma unroll
      for (int kk = 0; kk < 2; ++kk)
        pa[qs][kk] = *(const bf16x8*)&Ps[w][(qs * 16 + l15) * 64 +
                                            ((kk * 32 + l4 * 8) ^ psw)];
    #pragma unroll
    for (int ct2 = 0; ct2 < 4; ++ct2) {
      const int d   = ct2 * 16 + l15;
      const int vsw = ((d + (d >> 4)) & 7) << 3;
      bf16x8 vb0 = *(const bf16x8*)&Vt[d * 64 + ((l4 * 8) ^ vsw)];
      bf16x8 vb1 = *(const bf16x8*)&Vt[d * 64 + ((32 + l4 * 8) ^ vsw)];
      #pragma unroll
      for (int qs = 0; qs < 2; ++qs) {
        oacc[qs][ct2] = __builtin_amdgcn_mfma_f32_16x16x32_bf16(
            pa[qs][0], vb0, oacc[qs][ct2], 0, 0, 0);
        oacc[qs][ct2] = __builtin_amdgcn_mfma_f32_16x16x32_bf16(
            pa[qs][1], vb1, oacc[qs][ct2], 0, 0, 0);
      }
    }

    __syncthreads();                 // Ks[cur]/Vt reads done; drains prefetch vmcnt
    if (kt + 1 < nt) writeVt();      // install V(t+1)
    __syncthreads();                 // Vt visible to all waves
    cur ^= 1;
  }

  // ---- epilogue: O/l -> bf16 (O: col=d=l15+16*ct2, row=q=l4*4+r)
  #pragma unroll
  for (int qs = 0; qs < 2; ++qs)
    #pragma unroll
    for (int r = 0; r < 4; ++r) {
      const float lr  = __shfl(lrun[qs], l4 * 4 + r);
      const float inv = 1.0f / lr;
      const int qg = q0w + qs * 16 + l4 * 4 + r;
      ushort_t* dst = out + (size_t)(b * TSEQ + qg) * E_ + hd * 64 + l15;
      #pragma unroll
      for (int ct2 = 0; ct2 < 4; ++ct2)
        dst[ct2 * 16] = f2bf(oacc[qs][ct2][r] * inv);
    }
}

// ---------------------------------------------------------------- launcher
extern "C" void kernel_launch(void* const* d_in, const int* in_sizes, int n_in,
                              void* d_out, int out_size, void* d_ws, size_t ws_size,
                              hipStream_t stream) {
  const float* x          = (const float*)d_in[0];
  const float* ln1_g      = (const float*)d_in[1];
  const float* ln1_b      = (const float*)d_in[2];
  const float* w_attn     = (const float*)d_in[3];
  const float* b_attn     = (const float*)d_in[4];
  const float* w_attnproj = (const float*)d_in[5];
  const float* b_attnproj = (const float*)d_in[6];
  const float* ln2_g      = (const float*)d_in[7];
  const float* ln2_b      = (const float*)d_in[8];
  const float* w_fc       = (const float*)d_in[9];
  const float* b_fc       = (const float*)d_in[10];
  const float* w_proj     = (const float*)d_in[11];
  const float* b_proj     = (const float*)d_in[12];
  float* out = (float*)d_out;

  char* ws = (char*)d_ws;
  const size_t MB = 1024 * 1024;
  ushort_t* qkv      = (ushort_t*)ws;                    // 48 MB bf16
  ushort_t* h_bf     = (ushort_t*)ws;                    // 64 MB bf16 (alias)
  ushort_t* xn       = (ushort_t*)(ws + 64 * MB);        // 16 MB
  ushort_t* attnout  = (ushort_t*)(ws + 80 * MB);        // 16 MB
  float*    x1       = (float*)(ws + 96 * MB);           // 32 MB
  ushort_t* w_attnT  = (ushort_t*)(ws + 128 * MB);       // 6 MB  [3072][1024]
  ushort_t* w_aprojT = w_attnT  + (size_t)3 * E_ * E_;   // 2 MB  [1024][1024]
  ushort_t* w_fcT    = w_aprojT + (size_t)E_ * E_;       // 8 MB  [4096][1024]
  ushort_t* w_projT  = w_fcT    + (size_t)4 * E_ * E_;   // 8 MB  [1024][4096]

  castT_kernel<<<dim3(3 * E_ / 64, E_ / 32), 256, 0, stream>>>(w_attn, w_attnT, E_, 3 * E_);
  castT_kernel<<<dim3(E_ / 64, E_ / 32), 256, 0, stream>>>(w_attnproj, w_aprojT, E_, E_);
  castT_kernel<<<dim3(4 * E_ / 64, E_ / 32), 256, 0, stream>>>(w_fc, w_fcT, E_, 4 * E_);
  castT_kernel<<<dim3(E_ / 64, 4 * E_ / 32), 256, 0, stream>>>(w_proj, w_projT, 4 * E_, E_);

  // 1) xn1 = LN(x) -> bf16
  ln_kernel<<<MROWS, 256, 0, stream>>>(x, ln1_g, ln1_b, xn);
  // 2) qkv = xn1 @ w_attn + b_attn -> bf16
  gemm_kernel<0, 0, 1><<<dim3(3 * E_ / 128, MROWS / 128), 256, 0, stream>>>(
      xn, w_attnT, b_attn, nullptr, qkv, MROWS, 3 * E_, E_);
  // 3) attnout = causal_attention(qkv) -> bf16
  attn_kernel<<<dim3(TSEQ / 128, BATCH * NHEAD), 256, 0, stream>>>(qkv, attnout);
  // 4) x1 = x + attnout @ w_attnproj + b_attnproj -> f32
  gemm_kernel<0, 1, 0><<<dim3(E_ / 128, MROWS / 128), 256, 0, stream>>>(
      attnout, w_aprojT, b_attnproj, x, x1, MROWS, E_, E_);
  // 5) xn2 = LN(x1) -> bf16
  ln_kernel<<<MROWS, 256, 0, stream>>>(x1, ln2_g, ln2_b, xn);
  // 6) h = gelu(xn2 @ w_fc + b_fc) -> bf16 (region0, qkv dead)
  gemm_kernel<1, 0, 1><<<dim3(4 * E_ / 128, MROWS / 128), 256, 0, stream>>>(
      xn, w_fcT, b_fc, nullptr, h_bf, MROWS, 4 * E_, E_);
  // 7) out = x1 + h @ w_proj + b_proj -> f32
  gemm_kernel<0, 1, 0><<<dim3(E_ / 128, MROWS / 128), 256, 0, stream>>>(
      h_bf, w_projT, b_proj, x1, out, MROWS, E_, 4 * E_);
}

// Round 7
// 641.700 us; speedup vs baseline: 1.1678x; 1.0272x over previous
//
#include <hip/hip_runtime.h>
#include <math.h>

// GPT block forward. bf16 MFMA GEMMs (256-tile, 8-wave, double-buffered
// 2-phase) + bf16 MFMA flash attention (swapped QK^T, exp2-domain softmax,
// defer-max, LDS P-transpose, 1 barrier/tile).
// Shapes: B=4, T=2048, E=1024, H=16, D=64, M=B*T=8192.

constexpr int E_    = 1024;
constexpr int NHEAD = 16;
constexpr int BATCH = 4;
constexpr int TSEQ  = 2048;
constexpr int MROWS = BATCH * TSEQ;   // 8192

typedef unsigned short ushort_t;
typedef short  bf16x8 __attribute__((ext_vector_type(8)));
typedef float  f32x4  __attribute__((ext_vector_type(4)));
typedef unsigned short u16x4 __attribute__((ext_vector_type(4)));
typedef unsigned short u16x8 __attribute__((ext_vector_type(8)));

__device__ __forceinline__ ushort_t f2bf(float f) {
  unsigned u = __float_as_uint(f);
  unsigned r = (u + 0x7fffu + ((u >> 16) & 1u)) >> 16;
  return (ushort_t)r;
}

__device__ __forceinline__ void gload_lds16(const void* g, void* l) {
  __builtin_amdgcn_global_load_lds(
      (const __attribute__((address_space(1))) void*)g,
      (__attribute__((address_space(3))) void*)l, 16, 0, 0);
}

// ------------------------------------------------- weight cast + transpose
__global__ __launch_bounds__(256) void castT_kernel(const float* __restrict__ W,
                                                    ushort_t* __restrict__ Wt,
                                                    int K, int N) {
  const int n = blockIdx.x * 64 + (threadIdx.x & 63);
  const int k = blockIdx.y * 32 + (threadIdx.x >> 6) * 8;
  ushort_t v[8];
  #pragma unroll
  for (int u = 0; u < 8; ++u) v[u] = f2bf(W[(size_t)(k + u) * N + n]);
  *(u16x8*)&Wt[(size_t)n * K + k] = *(const u16x8*)v;
}

// ---------------------------------------------------------------- LayerNorm
__global__ __launch_bounds__(256) void ln_kernel(const float* __restrict__ x,
                                                 const float* __restrict__ g,
                                                 const float* __restrict__ b,
                                                 ushort_t* __restrict__ y) {
  const int row = blockIdx.x;
  const float4* xr = reinterpret_cast<const float4*>(x + (size_t)row * E_);
  float4 v = xr[threadIdx.x];
  float s  = v.x + v.y + v.z + v.w;
  float ss = v.x * v.x + v.y * v.y + v.z * v.z + v.w * v.w;
  #pragma unroll
  for (int off = 32; off > 0; off >>= 1) {
    s  += __shfl_down(s, off);
    ss += __shfl_down(ss, off);
  }
  __shared__ float red[8];
  __shared__ float stats[2];
  const int wid = threadIdx.x >> 6;
  if ((threadIdx.x & 63) == 0) { red[wid] = s; red[4 + wid] = ss; }
  __syncthreads();
  if (threadIdx.x == 0) {
    float S  = red[0] + red[1] + red[2] + red[3];
    float SS = red[4] + red[5] + red[6] + red[7];
    float mu  = S * (1.0f / E_);
    float var = SS * (1.0f / E_) - mu * mu;
    stats[0] = mu;
    stats[1] = rsqrtf(var + 1e-5f);
  }
  __syncthreads();
  const float mu = stats[0], rstd = stats[1];
  float4 gv = reinterpret_cast<const float4*>(g)[threadIdx.x];
  float4 bv = reinterpret_cast<const float4*>(b)[threadIdx.x];
  u16x4 o;
  o[0] = f2bf((v.x - mu) * rstd * gv.x + bv.x);
  o[1] = f2bf((v.y - mu) * rstd * gv.y + bv.y);
  o[2] = f2bf((v.z - mu) * rstd * gv.z + bv.z);
  o[3] = f2bf((v.w - mu) * rstd * gv.w + bv.w);
  *(u16x4*)(y + (size_t)row * E_ + threadIdx.x * 4) = o;
}

// ------------------------------------------------------------ bf16 MFMA GEMM
// C[M,N] = A[M,K](bf16) @ Wt[N,K](bf16)^T + bias (+GELU) (+res f32).
// 256xBN tile, BK=64, 512 thr = 8 waves (WM x WN), double-buffered LDS,
// 2-phase: stage(next) issued before compute(cur), ONE barrier per K-step.
template <int BN, int WM, int WN, int GELU, int RES, int OBF>
__global__ __launch_bounds__(512) void gemm2_kernel(
    const ushort_t* __restrict__ A, const ushort_t* __restrict__ Wt,
    const float* __restrict__ bias, const float* __restrict__ res,
    void* __restrict__ Cout, int M, int N, int K) {
  constexpr int BM = 256, BK = 64;
  constexpr int WMR = BM / WM;   // rows per wave
  constexpr int WNC = BN / WN;   // cols per wave
  constexpr int MR  = WMR / 16;
  constexpr int NR  = WNC / 16;
  extern __shared__ ushort_t smem[];
  ushort_t* As = smem;                         // [2][BM*BK]
  ushort_t* Bs = smem + 2 * BM * BK;           // [2][BN*BK]

  const int t = threadIdx.x, lane = t & 63, w = t >> 6;
  const int wr = w / WN, wc = w % WN;
  const int bm = blockIdx.y * BM, bn = blockIdx.x * BN;
  const int l15 = lane & 15, l4 = lane >> 4;

  f32x4 acc[MR][NR];
  #pragma unroll
  for (int mi = 0; mi < MR; ++mi)
    #pragma unroll
    for (int ni = 0; ni < NR; ++ni) acc[mi][ni] = f32x4{0.f, 0.f, 0.f, 0.f};

  // staging: per op, 512 thr cover 64 rows x 64 k (16B each). Wave w covers
  // rows w*8..w*8+7 (LDS dest wave-uniform base + lane*16).
  const ushort_t* gA = A  + (size_t)(bm + (t >> 3)) * K + (t & 7) * 8;
  const ushort_t* gB = Wt + (size_t)(bn + (t >> 3)) * K + (t & 7) * 8;

  auto stage = [&](int buf, int k0) {
    #pragma unroll
    for (int i = 0; i < BM / 64; ++i)
      gload_lds16(gA + (size_t)(i * 64) * K + k0,
                  As + buf * BM * BK + (i * 64 + w * 8) * BK);
    #pragma unroll
    for (int i = 0; i < BN / 64; ++i)
      gload_lds16(gB + (size_t)(i * 64) * K + k0,
                  Bs + buf * BN * BK + (i * 64 + w * 8) * BK);
  };

  stage(0, 0);
  __syncthreads();
  int cur = 0;
  for (int k0 = 0; k0 < K; k0 += BK) {
    if (k0 + BK < K) stage(cur ^ 1, k0 + BK);   // prefetch under compute
    #pragma unroll
    for (int kk = 0; kk < 2; ++kk) {
      bf16x8 af[MR], bv[NR];
      #pragma unroll
      for (int mi = 0; mi < MR; ++mi)
        af[mi] = *(const bf16x8*)&As[cur * BM * BK +
                 (wr * WMR + mi * 16 + l15) * BK + kk * 32 + l4 * 8];
      #pragma unroll
      for (int ni = 0; ni < NR; ++ni)
        bv[ni] = *(const bf16x8*)&Bs[cur * BN * BK +
                 (wc * WNC + ni * 16 + l15) * BK + kk * 32 + l4 * 8];
      #pragma unroll
      for (int mi = 0; mi < MR; ++mi)
        #pragma unroll
        for (int ni = 0; ni < NR; ++ni)
          acc[mi][ni] = __builtin_amdgcn_mfma_f32_16x16x32_bf16(
              af[mi], bv[ni], acc[mi][ni], 0, 0, 0);
    }
    __syncthreads();   // reads of cur done + prefetch into cur^1 drained
    cur ^= 1;
  }

  float biasv[NR];
  #pragma unroll
  for (int ni = 0; ni < NR; ++ni)
    biasv[ni] = bias[bn + wc * WNC + ni * 16 + l15];
  const int ccol = bn + wc * WNC + l15;

  #pragma unroll
  for (int mi = 0; mi < MR; ++mi) {
    #pragma unroll
    for (int j = 0; j < 4; ++j) {
      const int row = bm + wr * WMR + mi * 16 + l4 * 4 + j;
      const size_t rbase = (size_t)row * N;
      #pragma unroll
      for (int ni = 0; ni < NR; ++ni) {
        float v = acc[mi][ni][j] + biasv[ni];
        if (GELU) v = 0.5f * v * (1.0f + erff(v * 0.70710678118654752f));
        if (RES)  v += res[rbase + ccol + ni * 16];
        if (OBF)  ((ushort_t*)Cout)[rbase + ccol + ni * 16] = f2bf(v);
        else      ((float*)Cout)[rbase + ccol + ni * 16] = v;
      }
    }
  }
}

// ---------------------------------------------------------- MFMA attention
// Causal flash attention. Swapped QK^T (S^T: col=q, row=k), exp2-domain
// online softmax with defer-max (T13), P transposed via per-wave LDS
// round-trip (R5-verified), K and Vt double-buffered -> 1 barrier/tile.
__global__ __launch_bounds__(256) void attn_kernel(const ushort_t* __restrict__ qkv,
                                                   ushort_t* __restrict__ out) {
  __shared__ ushort_t Ks[2][64 * 64];   // [k][d], chunk-swizzled (row&7)
  __shared__ ushort_t Vt[2][64 * 64];   // [d][k], swizzled key=(d+(d>>4))&7
  __shared__ ushort_t Ps[4][32 * 64];   // per-wave [q][k], swizzled (q&7)

  constexpr float CSCL = 0.18033688011112042f;  // 0.125 * log2(e)
  constexpr float THR2 = 11.5415603f;           // 8 * log2(e)

  const int qb  = (int)gridDim.x - 1 - (int)blockIdx.x;   // heavy blocks first
  const int b   = blockIdx.y >> 4;
  const int hd  = blockIdx.y & 15;
  const int t   = threadIdx.x;
  const int lane = t & 63, w = t >> 6;
  const int l15 = lane & 15, l4 = lane >> 4;

  const size_t rs3 = 3 * E_;
  const ushort_t* base = qkv + (size_t)b * TSEQ * rs3 + hd * 64;
  const int q0w = qb * 128 + w * 32;    // wave's min q row

  const int srow = t >> 2;              // V staging row
  const int sc0  = (t & 3) << 4;        // V staging col (16 d)

  bf16x8 qf[2][2];
  #pragma unroll
  for (int qs = 0; qs < 2; ++qs)
    #pragma unroll
    for (int kk = 0; kk < 2; ++kk)
      qf[qs][kk] = *(const bf16x8*)(base +
          (size_t)(q0w + qs * 16 + l15) * rs3 + kk * 32 + l4 * 8);

  float mrun[2], lrun[2];
  f32x4 oacc[2][4];
  #pragma unroll
  for (int qs = 0; qs < 2; ++qs) {
    mrun[qs] = -INFINITY; lrun[qs] = 0.f;
    #pragma unroll
    for (int c = 0; c < 4; ++c) oacc[qs][c] = f32x4{0.f, 0.f, 0.f, 0.f};
  }

  u16x8 v0, v1;   // V prefetch registers

  auto loadV = [&](int kt) {
    const ushort_t* vsrc = base + 2 * E_ + (size_t)(kt * 64 + srow) * rs3 + sc0;
    v0 = *(const u16x8*)vsrc;
    v1 = *(const u16x8*)(vsrc + 8);
  };
  auto stageK = [&](int kt, int buf) {
    #pragma unroll
    for (int c = 0; c < 2; ++c) {
      const int lrow  = w * 16 + c * 8 + (lane >> 3);
      const int chunk = (lane & 7) ^ (lane >> 3);   // inverse swizzle on source
      gload_lds16(base + E_ + (size_t)(kt * 64 + lrow) * rs3 + chunk * 8,
                  &Ks[buf][(w * 16 + c * 8) * 64]);
    }
  };
  auto writeVt = [&](int buf) {
    #pragma unroll
    for (int j = 0; j < 8; ++j) {
      const int d0 = sc0 + j;
      const int d1 = sc0 + 8 + j;
      Vt[buf][d0 * 64 + (srow ^ (((d0 + (d0 >> 4)) & 7) << 3))] = v0[j];
      Vt[buf][d1 * 64 + (srow ^ (((d1 + (d1 >> 4)) & 7) << 3))] = v1[j];
    }
  };

  // prologue
  loadV(0);
  stageK(0, 0);
  writeVt(0);
  __syncthreads();

  const int nt = 2 * qb + 2;
  int cur = 0;
  const f32x4 zero = {0.f, 0.f, 0.f, 0.f};

  for (int kt = 0; kt < nt; ++kt) {
    if (kt + 1 < nt) { loadV(kt + 1); stageK(kt + 1, cur ^ 1); }

    const int ktb = kt * 64;
    if (ktb <= q0w + 31) {   // wave-level skip of fully-masked tail tiles
      // ---- S^T = K Q^T : col=q=l15(+16qs), row=k=ct*16+l4*4+r
      f32x4 s[2][4];
      #pragma unroll
      for (int ct = 0; ct < 4; ++ct) {
        const int krow = ct * 16 + l15;
        const int ksw  = (krow & 7) << 3;
        bf16x8 kf0 = *(const bf16x8*)&Ks[cur][krow * 64 + ((l4 * 8) ^ ksw)];
        bf16x8 kf1 = *(const bf16x8*)&Ks[cur][krow * 64 + ((32 + l4 * 8) ^ ksw)];
        #pragma unroll
        for (int qs = 0; qs < 2; ++qs) {
          f32x4 a0 = __builtin_amdgcn_mfma_f32_16x16x32_bf16(kf0, qf[qs][0], zero, 0, 0, 0);
          s[qs][ct] = __builtin_amdgcn_mfma_f32_16x16x32_bf16(kf1, qf[qs][1], a0, 0, 0, 0);
        }
      }

      // ---- scale into log2 domain + causal mask (diagonal tiles only)
      const bool domask = (ktb + 63 > q0w);
      #pragma unroll
      for (int qs = 0; qs < 2; ++qs)
        #pragma unroll
        for (int ct = 0; ct < 4; ++ct) {
          s[qs][ct] *= CSCL;
          if (domask) {
            const int q = q0w + qs * 16 + l15;
            #pragma unroll
            for (int r = 0; r < 4; ++r)
              if (ktb + ct * 16 + l4 * 4 + r > q) s[qs][ct][r] = -INFINITY;
          }
        }

      // ---- online softmax (exp2 domain, defer-max T13)
      #pragma unroll
      for (int qs = 0; qs < 2; ++qs) {
        float pmax = s[qs][0][0];
        #pragma unroll
        for (int ct = 0; ct < 4; ++ct)
          #pragma unroll
          for (int r = 0; r < 4; ++r) pmax = fmaxf(pmax, s[qs][ct][r]);
        pmax = fmaxf(pmax, __shfl_xor(pmax, 16));
        pmax = fmaxf(pmax, __shfl_xor(pmax, 32));
        if (!__all(pmax - mrun[qs] <= THR2)) {
          const float mnew = fmaxf(mrun[qs], pmax);
          const float esc  = exp2f(mrun[qs] - mnew);
          mrun[qs] = mnew;
          lrun[qs] *= esc;
          #pragma unroll
          for (int r = 0; r < 4; ++r) {
            const float eo = __shfl(esc, l4 * 4 + r);
            #pragma unroll
            for (int c = 0; c < 4; ++c) oacc[qs][c][r] *= eo;
          }
        }
        float rs = 0.f;
        #pragma unroll
        for (int ct = 0; ct < 4; ++ct)
          #pragma unroll
          for (int r = 0; r < 4; ++r) {
            const float pv = exp2f(s[qs][ct][r] - mrun[qs]);
            s[qs][ct][r] = pv;
            rs += pv;
          }
        rs += __shfl_xor(rs, 16);
        rs += __shfl_xor(rs, 32);
        lrun[qs] += rs;
      }

      // ---- P -> per-wave LDS (transpose D-layout -> A-frag layout),
      // wave-private: no barrier needed (compiler inserts lgkmcnt waits).
      const int psw = (l15 & 7) << 3;
      #pragma unroll
      for (int qs = 0; qs < 2; ++qs)
        #pragma unroll
        for (int ct = 0; ct < 4; ++ct) {
          u16x4 pk;
          #pragma unroll
          for (int r = 0; r < 4; ++r) pk[r] = f2bf(s[qs][ct][r]);
          *(u16x4*)&Ps[w][(qs * 16 + l15) * 64 + ((ct * 16 + l4 * 4) ^ psw)] = pk;
        }

      bf16x8 pa[2][2];
      #pragma unroll
      for (int qs = 0; qs < 2; ++qs)
        #pragma unroll
        for (int kk = 0; kk < 2; ++kk)
          pa[qs][kk] = *(const bf16x8*)&Ps[w][(qs * 16 + l15) * 64 +
                                              ((kk * 32 + l4 * 8) ^ psw)];

      // ---- O += P V  (A=P rows=q, B=Vt rows=d)
      #pragma unroll
      for (int ct2 = 0; ct2 < 4; ++ct2) {
        const int d   = ct2 * 16 + l15;
        const int vsw = ((d + (d >> 4)) & 7) << 3;
        bf16x8 vb0 = *(const bf16x8*)&Vt[cur][d * 64 + ((l4 * 8) ^ vsw)];
        bf16x8 vb1 = *(const bf16x8*)&Vt[cur][d * 64 + ((32 + l4 * 8) ^ vsw)];
        #pragma unroll
        for (int qs = 0; qs < 2; ++qs) {
          oacc[qs][ct2] = __builtin_amdgcn_mfma_f32_16x16x32_bf16(
              pa[qs][0], vb0, oacc[qs][ct2], 0, 0, 0);
          oacc[qs][ct2] = __builtin_amdgcn_mfma_f32_16x16x32_bf16(
              pa[qs][1], vb1, oacc[qs][ct2], 0, 0, 0);
        }
      }
    }

    if (kt + 1 < nt) writeVt(cur ^ 1);   // waits V regs; K prefetch stays live
    __syncthreads();                     // drains K prefetch; Vt^1 visible
    cur ^= 1;
  }

  // ---- epilogue: O/l -> bf16 (O: col=d=l15+16*ct2, row=q=l4*4+r)
  #pragma unroll
  for (int qs = 0; qs < 2; ++qs)
    #pragma unroll
    for (int r = 0; r < 4; ++r) {
      const float lr  = __shfl(lrun[qs], l4 * 4 + r);
      const float inv = 1.0f / lr;
      const int qg = q0w + qs * 16 + l4 * 4 + r;
      ushort_t* dst = out + (size_t)(b * TSEQ + qg) * E_ + hd * 64 + l15;
      #pragma unroll
      for (int ct2 = 0; ct2 < 4; ++ct2)
        dst[ct2 * 16] = f2bf(oacc[qs][ct2][r] * inv);
    }
}

// ---------------------------------------------------------------- launcher
extern "C" void kernel_launch(void* const* d_in, const int* in_sizes, int n_in,
                              void* d_out, int out_size, void* d_ws, size_t ws_size,
                              hipStream_t stream) {
  const float* x          = (const float*)d_in[0];
  const float* ln1_g      = (const float*)d_in[1];
  const float* ln1_b      = (const float*)d_in[2];
  const float* w_attn     = (const float*)d_in[3];
  const float* b_attn     = (const float*)d_in[4];
  const float* w_attnproj = (const float*)d_in[5];
  const float* b_attnproj = (const float*)d_in[6];
  const float* ln2_g      = (const float*)d_in[7];
  const float* ln2_b      = (const float*)d_in[8];
  const float* w_fc       = (const float*)d_in[9];
  const float* b_fc       = (const float*)d_in[10];
  const float* w_proj     = (const float*)d_in[11];
  const float* b_proj     = (const float*)d_in[12];
  float* out = (float*)d_out;

  char* ws = (char*)d_ws;
  const size_t MB = 1024 * 1024;
  ushort_t* qkv      = (ushort_t*)ws;                    // 48 MB bf16
  ushort_t* h_bf     = (ushort_t*)ws;                    // 64 MB bf16 (alias)
  ushort_t* xn       = (ushort_t*)(ws + 64 * MB);        // 16 MB
  ushort_t* attnout  = (ushort_t*)(ws + 80 * MB);        // 16 MB
  float*    x1       = (float*)(ws + 96 * MB);           // 32 MB
  ushort_t* w_attnT  = (ushort_t*)(ws + 128 * MB);       // 6 MB  [3072][1024]
  ushort_t* w_aprojT = w_attnT  + (size_t)3 * E_ * E_;   // 2 MB  [1024][1024]
  ushort_t* w_fcT    = w_aprojT + (size_t)E_ * E_;       // 8 MB  [4096][1024]
  ushort_t* w_projT  = w_fcT    + (size_t)4 * E_ * E_;   // 8 MB  [1024][4096]

  constexpr int SM256 = (256 + 256) * 64 * 2 * 2;   // 128 KiB
  constexpr int SM128 = (256 + 128) * 64 * 2 * 2;   //  96 KiB
  // unconditional (harness: same work every call); host-side, not stream ops
  hipFuncSetAttribute((const void*)gemm2_kernel<256, 2, 4, 0, 0, 1>,
                      hipFuncAttributeMaxDynamicSharedMemorySize, SM256);
  hipFuncSetAttribute((const void*)gemm2_kernel<256, 2, 4, 1, 0, 1>,
                      hipFuncAttributeMaxDynamicSharedMemorySize, SM256);
  hipFuncSetAttribute((const void*)gemm2_kernel<128, 4, 2, 0, 1, 0>,
                      hipFuncAttributeMaxDynamicSharedMemorySize, SM128);

  castT_kernel<<<dim3(3 * E_ / 64, E_ / 32), 256, 0, stream>>>(w_attn, w_attnT, E_, 3 * E_);
  castT_kernel<<<dim3(E_ / 64, E_ / 32), 256, 0, stream>>>(w_attnproj, w_aprojT, E_, E_);
  castT_kernel<<<dim3(4 * E_ / 64, E_ / 32), 256, 0, stream>>>(w_fc, w_fcT, E_, 4 * E_);
  castT_kernel<<<dim3(E_ / 64, 4 * E_ / 32), 256, 0, stream>>>(w_proj, w_projT, 4 * E_, E_);

  // 1) xn1 = LN(x) -> bf16
  ln_kernel<<<MROWS, 256, 0, stream>>>(x, ln1_g, ln1_b, xn);
  // 2) qkv = xn1 @ w_attn + b_attn -> bf16
  gemm2_kernel<256, 2, 4, 0, 0, 1><<<dim3(3 * E_ / 256, MROWS / 256), 512, SM256, stream>>>(
      xn, w_attnT, b_attn, nullptr, qkv, MROWS, 3 * E_, E_);
  // 3) attnout = causal_attention(qkv) -> bf16
  attn_kernel<<<dim3(TSEQ / 128, BATCH * NHEAD), 256, 0, stream>>>(qkv, attnout);
  // 4) x1 = x + attnout @ w_attnproj + b_attnproj -> f32
  gemm2_kernel<128, 4, 2, 0, 1, 0><<<dim3(E_ / 128, MROWS / 256), 512, SM128, stream>>>(
      attnout, w_aprojT, b_attnproj, x, x1, MROWS, E_, E_);
  // 5) xn2 = LN(x1) -> bf16
  ln_kernel<<<MROWS, 256, 0, stream>>>(x1, ln2_g, ln2_b, xn);
  // 6) h = gelu(xn2 @ w_fc + b_fc) -> bf16 (region0, qkv dead)
  gemm2_kernel<256, 2, 4, 1, 0, 1><<<dim3(4 * E_ / 256, MROWS / 256), 512, SM256, stream>>>(
      xn, w_fcT, b_fc, nullptr, h_bf, MROWS, 4 * E_, E_);
  // 7) out = x1 + h @ w_proj + b_proj -> f32
  gemm2_kernel<128, 4, 2, 0, 1, 0><<<dim3(E_ / 128, MROWS / 256), 512, SM128, stream>>>(
      h_bf, w_projT, b_proj, x1, out, MROWS, E_, 4 * E_);
}

// Round 8
// 586.654 us; speedup vs baseline: 1.2774x; 1.0938x over previous
//
#include <hip/hip_runtime.h>
#include <math.h>

// GPT block forward. bf16 MFMA GEMMs (256-tile, 2-phase, T2 LDS swizzle,
// XCD grid swizzle) + bf16 MFMA flash attention (swapped QK^T, exp2 softmax,
// defer-max, R5 sync structure: single Vt, 40KB LDS).
// Shapes: B=4, T=2048, E=1024, H=16, D=64, M=B*T=8192.

constexpr int E_    = 1024;
constexpr int NHEAD = 16;
constexpr int BATCH = 4;
constexpr int TSEQ  = 2048;
constexpr int MROWS = BATCH * TSEQ;   // 8192

typedef unsigned short ushort_t;
typedef short  bf16x8 __attribute__((ext_vector_type(8)));
typedef float  f32x4  __attribute__((ext_vector_type(4)));
typedef unsigned short u16x4 __attribute__((ext_vector_type(4)));
typedef unsigned short u16x8 __attribute__((ext_vector_type(8)));

__device__ __forceinline__ ushort_t f2bf(float f) {
  unsigned u = __float_as_uint(f);
  unsigned r = (u + 0x7fffu + ((u >> 16) & 1u)) >> 16;
  return (ushort_t)r;
}

__device__ __forceinline__ void gload_lds16(const void* g, void* l) {
  __builtin_amdgcn_global_load_lds(
      (const __attribute__((address_space(1))) void*)g,
      (__attribute__((address_space(3))) void*)l, 16, 0, 0);
}

// ------------------------------------------------- weight cast + transpose
__global__ __launch_bounds__(256) void castT_kernel(const float* __restrict__ W,
                                                    ushort_t* __restrict__ Wt,
                                                    int K, int N) {
  const int n = blockIdx.x * 64 + (threadIdx.x & 63);
  const int k = blockIdx.y * 32 + (threadIdx.x >> 6) * 8;
  ushort_t v[8];
  #pragma unroll
  for (int u = 0; u < 8; ++u) v[u] = f2bf(W[(size_t)(k + u) * N + n]);
  *(u16x8*)&Wt[(size_t)n * K + k] = *(const u16x8*)v;
}

// ---------------------------------------------------------------- LayerNorm
__global__ __launch_bounds__(256) void ln_kernel(const float* __restrict__ x,
                                                 const float* __restrict__ g,
                                                 const float* __restrict__ b,
                                                 ushort_t* __restrict__ y) {
  const int row = blockIdx.x;
  const float4* xr = reinterpret_cast<const float4*>(x + (size_t)row * E_);
  float4 v = xr[threadIdx.x];
  float s  = v.x + v.y + v.z + v.w;
  float ss = v.x * v.x + v.y * v.y + v.z * v.z + v.w * v.w;
  #pragma unroll
  for (int off = 32; off > 0; off >>= 1) {
    s  += __shfl_down(s, off);
    ss += __shfl_down(ss, off);
  }
  __shared__ float red[8];
  __shared__ float stats[2];
  const int wid = threadIdx.x >> 6;
  if ((threadIdx.x & 63) == 0) { red[wid] = s; red[4 + wid] = ss; }
  __syncthreads();
  if (threadIdx.x == 0) {
    float S  = red[0] + red[1] + red[2] + red[3];
    float SS = red[4] + red[5] + red[6] + red[7];
    float mu  = S * (1.0f / E_);
    float var = SS * (1.0f / E_) - mu * mu;
    stats[0] = mu;
    stats[1] = rsqrtf(var + 1e-5f);
  }
  __syncthreads();
  const float mu = stats[0], rstd = stats[1];
  float4 gv = reinterpret_cast<const float4*>(g)[threadIdx.x];
  float4 bv = reinterpret_cast<const float4*>(b)[threadIdx.x];
  u16x4 o;
  o[0] = f2bf((v.x - mu) * rstd * gv.x + bv.x);
  o[1] = f2bf((v.y - mu) * rstd * gv.y + bv.y);
  o[2] = f2bf((v.z - mu) * rstd * gv.z + bv.z);
  o[3] = f2bf((v.w - mu) * rstd * gv.w + bv.w);
  *(u16x4*)(y + (size_t)row * E_ + threadIdx.x * 4) = o;
}

// ------------------------------------------------------------ bf16 MFMA GEMM
// C[M,N] = A[M,K](bf16) @ Wt[N,K](bf16)^T + bias (+GELU) (+res f32).
// 256xBN tile, BK=64, 8 waves, double-buffered LDS, 2-phase, T2 XOR swizzle:
// LDS row r stores global chunk c at slot c^(r&7) (chunk = 8 u16 = 16B);
// achieved via inverse-swizzled per-lane GLOBAL source (linear LDS dest,
// rule #21) and ^(l15&7) on fragment reads -> 2 lanes/bank (free).
template <int BN, int WM, int WN, int GELU, int RES, int OBF>
__global__ __launch_bounds__(512) void gemm2_kernel(
    const ushort_t* __restrict__ A, const ushort_t* __restrict__ Wt,
    const float* __restrict__ bias, const float* __restrict__ res,
    void* __restrict__ Cout, int M, int N, int K) {
  constexpr int BM = 256, BK = 64;
  constexpr int WMR = BM / WM;
  constexpr int WNC = BN / WN;
  constexpr int MR  = WMR / 16;
  constexpr int NR  = WNC / 16;
  extern __shared__ ushort_t smem[];
  ushort_t* As = smem;                         // [2][BM*BK]
  ushort_t* Bs = smem + 2 * BM * BK;           // [2][BN*BK]

  const int t = threadIdx.x, lane = t & 63, w = t >> 6;
  const int wr = w / WN, wc = w % WN;

  // T1: bijective XCD swizzle of the block id (nwg % 8 == 0 for all grids)
  const int nwg = gridDim.x * gridDim.y;
  const int lin = blockIdx.y * gridDim.x + blockIdx.x;
  const int swz = (lin & 7) * (nwg >> 3) + (lin >> 3);
  const int bm  = (swz / gridDim.x) * BM;
  const int bn  = (swz % gridDim.x) * BN;

  const int l15 = lane & 15, l4 = lane >> 4;
  const int sw16 = (l15 & 7) << 3;   // read-side chunk XOR (u16 units)

  f32x4 acc[MR][NR];
  #pragma unroll
  for (int mi = 0; mi < MR; ++mi)
    #pragma unroll
    for (int ni = 0; ni < NR; ++ni) acc[mi][ni] = f32x4{0.f, 0.f, 0.f, 0.f};

  // staging: thread t covers row (t>>3) of each 64-row chunk, global chunk
  // (t&7)^((t>>3)&7)  -> linear LDS slot (t&7) holds swizzled layout.
  const int scol = ((t & 7) ^ ((t >> 3) & 7)) * 8;
  const ushort_t* gA = A  + (size_t)(bm + (t >> 3)) * K + scol;
  const ushort_t* gB = Wt + (size_t)(bn + (t >> 3)) * K + scol;

  auto stage = [&](int buf, int k0) {
    #pragma unroll
    for (int i = 0; i < BM / 64; ++i)
      gload_lds16(gA + (size_t)(i * 64) * K + k0,
                  As + buf * BM * BK + (i * 64 + w * 8) * BK);
    #pragma unroll
    for (int i = 0; i < BN / 64; ++i)
      gload_lds16(gB + (size_t)(i * 64) * K + k0,
                  Bs + buf * BN * BK + (i * 64 + w * 8) * BK);
  };

  stage(0, 0);
  __syncthreads();
  int cur = 0;
  for (int k0 = 0; k0 < K; k0 += BK) {
    if (k0 + BK < K) stage(cur ^ 1, k0 + BK);   // prefetch under compute
    #pragma unroll
    for (int kk = 0; kk < 2; ++kk) {
      bf16x8 af[MR], bv[NR];
      #pragma unroll
      for (int mi = 0; mi < MR; ++mi)
        af[mi] = *(const bf16x8*)&As[cur * BM * BK +
                 (wr * WMR + mi * 16 + l15) * BK + ((kk * 32 + l4 * 8) ^ sw16)];
      #pragma unroll
      for (int ni = 0; ni < NR; ++ni)
        bv[ni] = *(const bf16x8*)&Bs[cur * BN * BK +
                 (wc * WNC + ni * 16 + l15) * BK + ((kk * 32 + l4 * 8) ^ sw16)];
      #pragma unroll
      for (int mi = 0; mi < MR; ++mi)
        #pragma unroll
        for (int ni = 0; ni < NR; ++ni)
          acc[mi][ni] = __builtin_amdgcn_mfma_f32_16x16x32_bf16(
              af[mi], bv[ni], acc[mi][ni], 0, 0, 0);
    }
    __syncthreads();
    cur ^= 1;
  }

  float biasv[NR];
  #pragma unroll
  for (int ni = 0; ni < NR; ++ni)
    biasv[ni] = bias[bn + wc * WNC + ni * 16 + l15];
  const int ccol = bn + wc * WNC + l15;

  #pragma unroll
  for (int mi = 0; mi < MR; ++mi) {
    #pragma unroll
    for (int j = 0; j < 4; ++j) {
      const int row = bm + wr * WMR + mi * 16 + l4 * 4 + j;
      const size_t rbase = (size_t)row * N;
      #pragma unroll
      for (int ni = 0; ni < NR; ++ni) {
        float v = acc[mi][ni][j] + biasv[ni];
        if (GELU) v = 0.5f * v * (1.0f + erff(v * 0.70710678118654752f));
        if (RES)  v += res[rbase + ccol + ni * 16];
        if (OBF)  ((ushort_t*)Cout)[rbase + ccol + ni * 16] = f2bf(v);
        else      ((float*)Cout)[rbase + ccol + ni * 16] = v;
      }
    }
  }
}

// ---------------------------------------------------------- MFMA attention
// Causal flash attention. Swapped QK^T, exp2-domain online softmax with
// defer-max (T13), per-wave LDS P-transpose. R5-measured sync structure:
// double-buffered Ks (gload_lds), SINGLE Vt + two barriers, 40KB LDS.
__global__ __launch_bounds__(256) void attn_kernel(const ushort_t* __restrict__ qkv,
                                                   ushort_t* __restrict__ out) {
  __shared__ ushort_t Ks[2][64 * 64];   // [k][d], chunk-swizzled (row&7)
  __shared__ ushort_t Vt[64 * 64];      // [d][k], swizzled key=(d+(d>>4))&7
  __shared__ ushort_t Ps[4][32 * 64];   // per-wave [q][k], swizzled (q&7)

  constexpr float CSCL = 0.18033688011112042f;  // 0.125 * log2(e)
  constexpr float THR2 = 11.5415603f;           // 8 * log2(e)

  // T1: bijective XCD swizzle (nwg=1024); same-bh blocks share an XCD's L2.
  const int nwg = gridDim.x * gridDim.y;
  const int lin = blockIdx.y * gridDim.x + blockIdx.x;
  const int swzb = (lin & 7) * (nwg >> 3) + (lin >> 3);
  const int bx = swzb & 15, by = swzb >> 4;

  const int qb  = 15 - bx;              // heavy blocks first within chunk
  const int b   = by >> 4;
  const int hd  = by & 15;
  const int t   = threadIdx.x;
  const int lane = t & 63, w = t >> 6;
  const int l15 = lane & 15, l4 = lane >> 4;

  const size_t rs3 = 3 * E_;
  const ushort_t* base = qkv + (size_t)b * TSEQ * rs3 + hd * 64;
  const int q0w = qb * 128 + w * 32;    // wave's min q row

  const int srow = t >> 2;              // V staging row
  const int sc0  = (t & 3) << 4;        // V staging col (16 d)

  bf16x8 qf[2][2];
  #pragma unroll
  for (int qs = 0; qs < 2; ++qs)
    #pragma unroll
    for (int kk = 0; kk < 2; ++kk)
      qf[qs][kk] = *(const bf16x8*)(base +
          (size_t)(q0w + qs * 16 + l15) * rs3 + kk * 32 + l4 * 8);

  float mrun[2], lrun[2];
  f32x4 oacc[2][4];
  #pragma unroll
  for (int qs = 0; qs < 2; ++qs) {
    mrun[qs] = -INFINITY; lrun[qs] = 0.f;
    #pragma unroll
    for (int c = 0; c < 4; ++c) oacc[qs][c] = f32x4{0.f, 0.f, 0.f, 0.f};
  }

  u16x8 v0, v1;   // V prefetch registers

  auto loadV = [&](int kt) {
    const ushort_t* vsrc = base + 2 * E_ + (size_t)(kt * 64 + srow) * rs3 + sc0;
    v0 = *(const u16x8*)vsrc;
    v1 = *(const u16x8*)(vsrc + 8);
  };
  auto stageK = [&](int kt, int buf) {
    #pragma unroll
    for (int c = 0; c < 2; ++c) {
      const int lrow  = w * 16 + c * 8 + (lane >> 3);
      const int chunk = (lane & 7) ^ (lane >> 3);   // inverse swizzle on source
      gload_lds16(base + E_ + (size_t)(kt * 64 + lrow) * rs3 + chunk * 8,
                  &Ks[buf][(w * 16 + c * 8) * 64]);
    }
  };
  auto writeVt = [&]() {
    #pragma unroll
    for (int j = 0; j < 8; ++j) {
      const int d0 = sc0 + j;
      const int d1 = sc0 + 8 + j;
      Vt[d0 * 64 + (srow ^ (((d0 + (d0 >> 4)) & 7) << 3))] = v0[j];
      Vt[d1 * 64 + (srow ^ (((d1 + (d1 >> 4)) & 7) << 3))] = v1[j];
    }
  };

  // prologue
  stageK(0, 0);
  loadV(0);
  writeVt();
  __syncthreads();

  const int nt = 2 * qb + 2;
  int cur = 0;
  const f32x4 zero = {0.f, 0.f, 0.f, 0.f};

  for (int kt = 0; kt < nt; ++kt) {
    if (kt + 1 < nt) { stageK(kt + 1, cur ^ 1); loadV(kt + 1); }

    const int ktb = kt * 64;
    if (ktb <= q0w + 31) {   // wave-level skip of fully-masked tail tiles
      // ---- S^T = K Q^T : col=q=l15(+16qs), row=k=ct*16+l4*4+r
      f32x4 s[2][4];
      #pragma unroll
      for (int ct = 0; ct < 4; ++ct) {
        const int krow = ct * 16 + l15;
        const int ksw  = (krow & 7) << 3;
        bf16x8 kf0 = *(const bf16x8*)&Ks[cur][krow * 64 + ((l4 * 8) ^ ksw)];
        bf16x8 kf1 = *(const bf16x8*)&Ks[cur][krow * 64 + ((32 + l4 * 8) ^ ksw)];
        #pragma unroll
        for (int qs = 0; qs < 2; ++qs) {
          f32x4 a0 = __builtin_amdgcn_mfma_f32_16x16x32_bf16(kf0, qf[qs][0], zero, 0, 0, 0);
          s[qs][ct] = __builtin_amdgcn_mfma_f32_16x16x32_bf16(kf1, qf[qs][1], a0, 0, 0, 0);
        }
      }

      // ---- scale into log2 domain + causal mask (diagonal tiles only)
      const bool domask = (ktb + 63 > q0w);
      #pragma unroll
      for (int qs = 0; qs < 2; ++qs)
        #pragma unroll
        for (int ct = 0; ct < 4; ++ct) {
          s[qs][ct] *= CSCL;
          if (domask) {
            const int q = q0w + qs * 16 + l15;
            #pragma unroll
            for (int r = 0; r < 4; ++r)
              if (ktb + ct * 16 + l4 * 4 + r > q) s[qs][ct][r] = -INFINITY;
          }
        }

      // ---- online softmax (exp2 domain, defer-max T13)
      #pragma unroll
      for (int qs = 0; qs < 2; ++qs) {
        float pmax = s[qs][0][0];
        #pragma unroll
        for (int ct = 0; ct < 4; ++ct)
          #pragma unroll
          for (int r = 0; r < 4; ++r) pmax = fmaxf(pmax, s[qs][ct][r]);
        pmax = fmaxf(pmax, __shfl_xor(pmax, 16));
        pmax = fmaxf(pmax, __shfl_xor(pmax, 32));
        if (!__all(pmax - mrun[qs] <= THR2)) {
          const float mnew = fmaxf(mrun[qs], pmax);
          const float esc  = exp2f(mrun[qs] - mnew);
          mrun[qs] = mnew;
          lrun[qs] *= esc;
          #pragma unroll
          for (int r = 0; r < 4; ++r) {
            const float eo = __shfl(esc, l4 * 4 + r);
            #pragma unroll
            for (int c = 0; c < 4; ++c) oacc[qs][c][r] *= eo;
          }
        }
        float rs = 0.f;
        #pragma unroll
        for (int ct = 0; ct < 4; ++ct)
          #pragma unroll
          for (int r = 0; r < 4; ++r) {
            const float pv = exp2f(s[qs][ct][r] - mrun[qs]);
            s[qs][ct][r] = pv;
            rs += pv;
          }
        rs += __shfl_xor(rs, 16);
        rs += __shfl_xor(rs, 32);
        lrun[qs] += rs;
      }

      // ---- P -> per-wave LDS (transpose D-layout -> A-frag layout)
      const int psw = (l15 & 7) << 3;
      #pragma unroll
      for (int qs = 0; qs < 2; ++qs)
        #pragma unroll
        for (int ct = 0; ct < 4; ++ct) {
          u16x4 pk;
          #pragma unroll
          for (int r = 0; r < 4; ++r) pk[r] = f2bf(s[qs][ct][r]);
          *(u16x4*)&Ps[w][(qs * 16 + l15) * 64 + ((ct * 16 + l4 * 4) ^ psw)] = pk;
        }

      bf16x8 pa[2][2];
      #pragma unroll
      for (int qs = 0; qs < 2; ++qs)
        #pragma unroll
        for (int kk = 0; kk < 2; ++kk)
          pa[qs][kk] = *(const bf16x8*)&Ps[w][(qs * 16 + l15) * 64 +
                                              ((kk * 32 + l4 * 8) ^ psw)];

      // ---- O += P V  (A=P rows=q, B=Vt rows=d)
      #pragma unroll
      for (int ct2 = 0; ct2 < 4; ++ct2) {
        const int d   = ct2 * 16 + l15;
        const int vsw = ((d + (d >> 4)) & 7) << 3;
        bf16x8 vb0 = *(const bf16x8*)&Vt[d * 64 + ((l4 * 8) ^ vsw)];
        bf16x8 vb1 = *(const bf16x8*)&Vt[d * 64 + ((32 + l4 * 8) ^ vsw)];
        #pragma unroll
        for (int qs = 0; qs < 2; ++qs) {
          oacc[qs][ct2] = __builtin_amdgcn_mfma_f32_16x16x32_bf16(
              pa[qs][0], vb0, oacc[qs][ct2], 0, 0, 0);
          oacc[qs][ct2] = __builtin_amdgcn_mfma_f32_16x16x32_bf16(
              pa[qs][1], vb1, oacc[qs][ct2], 0, 0, 0);
        }
      }
    }

    __syncthreads();                 // Vt reads done; drains K prefetch
    if (kt + 1 < nt) writeVt();      // install V(t+1)
    __syncthreads();                 // Vt visible
    cur ^= 1;
  }

  // ---- epilogue
  #pragma unroll
  for (int qs = 0; qs < 2; ++qs)
    #pragma unroll
    for (int r = 0; r < 4; ++r) {
      const float lr  = __shfl(lrun[qs], l4 * 4 + r);
      const float inv = 1.0f / lr;
      const int qg = q0w + qs * 16 + l4 * 4 + r;
      ushort_t* dst = out + (size_t)(b * TSEQ + qg) * E_ + hd * 64 + l15;
      #pragma unroll
      for (int ct2 = 0; ct2 < 4; ++ct2)
        dst[ct2 * 16] = f2bf(oacc[qs][ct2][r] * inv);
    }
}

// ---------------------------------------------------------------- launcher
extern "C" void kernel_launch(void* const* d_in, const int* in_sizes, int n_in,
                              void* d_out, int out_size, void* d_ws, size_t ws_size,
                              hipStream_t stream) {
  const float* x          = (const float*)d_in[0];
  const float* ln1_g      = (const float*)d_in[1];
  const float* ln1_b      = (const float*)d_in[2];
  const float* w_attn     = (const float*)d_in[3];
  const float* b_attn     = (const float*)d_in[4];
  const float* w_attnproj = (const float*)d_in[5];
  const float* b_attnproj = (const float*)d_in[6];
  const float* ln2_g      = (const float*)d_in[7];
  const float* ln2_b      = (const float*)d_in[8];
  const float* w_fc       = (const float*)d_in[9];
  const float* b_fc       = (const float*)d_in[10];
  const float* w_proj     = (const float*)d_in[11];
  const float* b_proj     = (const float*)d_in[12];
  float* out = (float*)d_out;

  char* ws = (char*)d_ws;
  const size_t MB = 1024 * 1024;
  ushort_t* qkv      = (ushort_t*)ws;                    // 48 MB bf16
  ushort_t* h_bf     = (ushort_t*)ws;                    // 64 MB bf16 (alias)
  ushort_t* xn       = (ushort_t*)(ws + 64 * MB);        // 16 MB
  ushort_t* attnout  = (ushort_t*)(ws + 80 * MB);        // 16 MB
  float*    x1       = (float*)(ws + 96 * MB);           // 32 MB
  ushort_t* w_attnT  = (ushort_t*)(ws + 128 * MB);       // 6 MB  [3072][1024]
  ushort_t* w_aprojT = w_attnT  + (size_t)3 * E_ * E_;   // 2 MB  [1024][1024]
  ushort_t* w_fcT    = w_aprojT + (size_t)E_ * E_;       // 8 MB  [4096][1024]
  ushort_t* w_projT  = w_fcT    + (size_t)4 * E_ * E_;   // 8 MB  [1024][4096]

  constexpr int SM256 = (256 + 256) * 64 * 2 * 2;   // 128 KiB
  constexpr int SM128 = (256 + 128) * 64 * 2 * 2;   //  96 KiB
  hipFuncSetAttribute((const void*)gemm2_kernel<256, 2, 4, 0, 0, 1>,
                      hipFuncAttributeMaxDynamicSharedMemorySize, SM256);
  hipFuncSetAttribute((const void*)gemm2_kernel<256, 2, 4, 1, 0, 1>,
                      hipFuncAttributeMaxDynamicSharedMemorySize, SM256);
  hipFuncSetAttribute((const void*)gemm2_kernel<128, 4, 2, 0, 1, 0>,
                      hipFuncAttributeMaxDynamicSharedMemorySize, SM128);

  castT_kernel<<<dim3(3 * E_ / 64, E_ / 32), 256, 0, stream>>>(w_attn, w_attnT, E_, 3 * E_);
  castT_kernel<<<dim3(E_ / 64, E_ / 32), 256, 0, stream>>>(w_attnproj, w_aprojT, E_, E_);
  castT_kernel<<<dim3(4 * E_ / 64, E_ / 32), 256, 0, stream>>>(w_fc, w_fcT, E_, 4 * E_);
  castT_kernel<<<dim3(E_ / 64, 4 * E_ / 32), 256, 0, stream>>>(w_proj, w_projT, 4 * E_, E_);

  // 1) xn1 = LN(x) -> bf16
  ln_kernel<<<MROWS, 256, 0, stream>>>(x, ln1_g, ln1_b, xn);
  // 2) qkv = xn1 @ w_attn + b_attn -> bf16
  gemm2_kernel<256, 2, 4, 0, 0, 1><<<dim3(3 * E_ / 256, MROWS / 256), 512, SM256, stream>>>(
      xn, w_attnT, b_attn, nullptr, qkv, MROWS, 3 * E_, E_);
  // 3) attnout = causal_attention(qkv) -> bf16
  attn_kernel<<<dim3(TSEQ / 128, BATCH * NHEAD), 256, 0, stream>>>(qkv, attnout);
  // 4) x1 = x + attnout @ w_attnproj + b_attnproj -> f32
  gemm2_kernel<128, 4, 2, 0, 1, 0><<<dim3(E_ / 128, MROWS / 256), 512, SM128, stream>>>(
      attnout, w_aprojT, b_attnproj, x, x1, MROWS, E_, E_);
  // 5) xn2 = LN(x1) -> bf16
  ln_kernel<<<MROWS, 256, 0, stream>>>(x1, ln2_g, ln2_b, xn);
  // 6) h = gelu(xn2 @ w_fc + b_fc) -> bf16 (region0, qkv dead)
  gemm2_kernel<256, 2, 4, 1, 0, 1><<<dim3(4 * E_ / 256, MROWS / 256), 512, SM256, stream>>>(
      xn, w_fcT, b_fc, nullptr, h_bf, MROWS, 4 * E_, E_);
  // 7) out = x1 + h @ w_proj + b_proj -> f32
  gemm2_kernel<128, 4, 2, 0, 1, 0><<<dim3(E_ / 128, MROWS / 256), 512, SM128, stream>>>(
      h_bf, w_projT, b_proj, x1, out, MROWS, E_, 4 * E_);
}